// Round 4
// baseline (305.542 us; speedup 1.0000x reference)
//
#include <hip/hip_runtime.h>
#include <stdint.h>

typedef unsigned long long u64;

#define CHUNK 2048      // elements per LDS sort chunk
#define CTHREADS 1024   // threads per chunk block (2 elems/thread)
#define LOG_CHUNK 11
#define NSEG 2048       // parallel PAVA segments (boundary cache fits 48KB LDS)

__device__ __forceinline__ void cmpswap(u64& a, u64& b, bool desc) {
  bool sw = desc ? (a < b) : (a > b);
  if (sw) { u64 t = a; a = b; b = t; }
}

// Build composite keys (bits(|u-x|)<<32 | ~idx) and fully sort each
// 2048-chunk in LDS. Descending u64 == stable argsort(-abs).
__global__ void k_sort_chunk(const float* __restrict__ u, const float* __restrict__ x,
                             u64* __restrict__ key, int n) {
  __shared__ u64 s[CHUNK];
  int base = blockIdx.x * CHUNK;
  for (int q = 0; q < 2; ++q) {
    int g = base + threadIdx.x + q * CTHREADS;
    u64 kk = 0ull;
    if (g < n) {
      float d = u[g] - x[g];
      kk = ((u64)__float_as_uint(fabsf(d)) << 32) | (unsigned)(~(unsigned)g);
    }
    s[threadIdx.x + q * CTHREADS] = kk;
  }
  __syncthreads();
  for (int k = 2; k <= CHUNK; k <<= 1) {
    for (int j = k >> 1; j > 0; j >>= 1) {
      int t = threadIdx.x;
      int i = 2 * t - (t & (j - 1));
      bool desc = (((base + i) & k) == 0);
      cmpswap(s[i], s[i + j], desc);
      __syncthreads();
    }
  }
  key[base + threadIdx.x] = s[threadIdx.x];
  key[base + threadIdx.x + CTHREADS] = s[threadIdx.x + CTHREADS];
}

// Fused NL bitonic levels (j = 2^(p_lo+NL-1) .. 2^p_lo, all >= CHUNK) of
// stage k, done in registers: 2^NL keys per thread. All fused levels sit
// below bit log2(k), so the direction is uniform within the group.
template<int NL>
__global__ void k_merge_fused(u64* __restrict__ key, int k, int p_lo) {
  int t = blockIdx.x * blockDim.x + threadIdx.x;
  int jlo = 1 << p_lo;
  int low = t & (jlo - 1);
  int base = ((t >> p_lo) << (p_lo + NL)) | low;
  bool desc = ((base & k) == 0);
  u64 v[1 << NL];
#pragma unroll
  for (int m = 0; m < (1 << NL); ++m) v[m] = key[base + m * jlo];
#pragma unroll
  for (int lev = NL - 1; lev >= 0; --lev) {
    int st = 1 << lev;
#pragma unroll
    for (int m = 0; m < (1 << NL); ++m) {
      if ((m & st) == 0) cmpswap(v[m], v[m + st], desc);
    }
  }
#pragma unroll
  for (int m = 0; m < (1 << NL); ++m) key[base + m * jlo] = v[m];
}

// Fused j = 1024..1 levels of stage k, per 2048-chunk in LDS.
__global__ void k_merge_shared(u64* __restrict__ key, int k) {
  __shared__ u64 s[CHUNK];
  int base = blockIdx.x * CHUNK;
  s[threadIdx.x] = key[base + threadIdx.x];
  s[threadIdx.x + CTHREADS] = key[base + threadIdx.x + CTHREADS];
  __syncthreads();
  for (int j = CHUNK >> 1; j > 0; j >>= 1) {
    int t = threadIdx.x;
    int i = 2 * t - (t & (j - 1));
    bool desc = (((base + i) & k) == 0);
    cmpswap(s[i], s[i + j], desc);
    __syncthreads();
  }
  key[base + threadIdx.x] = s[threadIdx.x];
  key[base + threadIdx.x + CTHREADS] = s[threadIdx.x + CTHREADS];
}

// Per-thread sequential PAVA (non-increasing fit) on segment [tid*Lc, e).
// Top two stack pools in registers; spill slots in global (rarely re-read).
// Emits pools as linked list (sum/cnt at pool-start rank, cnt=0 elsewhere)
// plus compact per-segment boundary-pool arrays for the merge kernel.
__global__ void k_pava_seg(const u64* __restrict__ key, const float* __restrict__ w,
                           float* __restrict__ stkSum, float* __restrict__ stkCnt,
                           float* __restrict__ pSum, float* __restrict__ pCnt,
                           int* __restrict__ prv, int* __restrict__ nxt,
                           int* __restrict__ headR, int* __restrict__ tailR,
                           float* __restrict__ headS, float* __restrict__ headC,
                           float* __restrict__ tailS, float* __restrict__ tailC,
                           int n, int Lc) {
  int tid = blockIdx.x * blockDim.x + threadIdx.x;
  if (tid >= NSEG) return;
  int s = tid * Lc;
  int e = min(s + Lc, n);
  if (s >= e) { headR[tid] = -1; tailR[tid] = -1; return; }
  float ts = 0.f, tc = 0.f;   // top pool
  float ss = 0.f, sc = 0.f;   // second pool (valid when depth >= 1)
  int depth = 0;              // pools below top; slots 0..depth-2 in memory
  for (int r = s; r < e; ++r) {
    u64 kk = key[r];
    float yv = __uint_as_float((unsigned)(kk >> 32)) - w[r];
    if (r > s) {
      if (depth >= 1) { stkSum[s + depth - 1] = ss; stkCnt[s + depth - 1] = sc; }
      ss = ts; sc = tc; ++depth;
    }
    ts = yv; tc = 1.f;
    // merge while mean(top) > mean(second)  (cross-multiplied, cnts > 0)
    while (depth >= 1 && ts * sc > ss * tc) {
      ts += ss; tc += sc; --depth;
      if (depth >= 1) { ss = stkSum[s + depth - 1]; sc = stkCnt[s + depth - 1]; }
    }
  }
  // emit pools bottom-to-top; pool j starts at cumulative-count offset
  int prevStart = -1;
  int start = s;
  float hS = 0.f, hC = 0.f, lS = 0.f, lC = 0.f;
  for (int j = 0; j <= depth; ++j) {
    float sj, cj;
    if (j == depth)          { sj = ts; cj = tc; }
    else if (j == depth - 1) { sj = ss; cj = sc; }
    else                     { sj = stkSum[s + j]; cj = stkCnt[s + j]; }
    if (j == 0) { hS = sj; hC = cj; }
    lS = sj; lC = cj;
    pSum[start] = sj;
    pCnt[start] = cj;
    prv[start] = prevStart;
    if (prevStart >= 0) nxt[prevStart] = start;
    int c = (int)cj;
    for (int z = 1; z < c; ++z) pCnt[start + z] = 0.f;
    prevStart = start;
    start += c;
  }
  nxt[prevStart] = -1;
  headR[tid] = s;  tailR[tid] = prevStart;
  headS[tid] = hS; headC[tid] = hC;
  tailS[tid] = lS; tailC[tid] = lC;
}

// Hierarchical pairwise segment merge with LDS-cached group boundaries.
// Common path (no junction violation): LDS compare + 2 global stores, no
// dependent global loads. Rare cascades walk the global linked list.
// PAVA's fixed point is invariant to adjacent-merge order, so this is exact.
__global__ void k_merge_pools(float* __restrict__ pSum, float* __restrict__ pCnt,
                              int* __restrict__ prv, int* __restrict__ nxt,
                              const int* __restrict__ headR, const int* __restrict__ tailR,
                              const float* __restrict__ headS, const float* __restrict__ headC,
                              const float* __restrict__ tailS, const float* __restrict__ tailC) {
  __shared__ int shR[NSEG], stRk[NSEG];
  __shared__ float shS[NSEG], shC[NSEG], stS[NSEG], stC[NSEG];
  for (int i = threadIdx.x; i < NSEG; i += blockDim.x) {
    shR[i] = headR[i]; stRk[i] = tailR[i];
    shS[i] = headS[i]; shC[i] = headC[i];
    stS[i] = tailS[i]; stC[i] = tailC[i];
  }
  __syncthreads();
  for (int step = 1; step < NSEG; step <<= 1) {
    int pairs = NSEG / (2 * step);
    for (int p = threadIdx.x; p < pairs; p += blockDim.x) {
      int sL = p * 2 * step, sR = sL + step;
      int rR = shR[sR];
      if (rR < 0) continue;               // right group empty
      if (shR[sL] < 0) {                  // left empty: adopt right
        shR[sL] = rR; shS[sL] = shS[sR]; shC[sL] = shC[sR];
        stRk[sL] = stRk[sR]; stS[sL] = stS[sR]; stC[sL] = stC[sR];
        continue;
      }
      int lR = stRk[sL];
      float lS = stS[sL], lC = stC[sL];
      float rS = shS[sR], rC = shC[sR];
      nxt[lR] = rR; prv[rR] = lR;         // stitch lists
      if (rS * lC > lS * rC) {
        // violation at junction: cascade merge in global linked list
        float MS = lS + rS, MC = lC + rC;
        int Mr = lR;
        bool rtail = (rR == stRk[sR]);
        pCnt[rR] = 0.f;
        int nx = nxt[rR];
        nxt[Mr] = nx; if (nx >= 0) prv[nx] = Mr;
        for (;;) {
          int pp = prv[Mr];
          if (pp >= 0) {
            float ps = pSum[pp], pc = pCnt[pp];
            if (MS * pc > ps * MC) {      // mean(M) > mean(left pool): absorb
              MS += ps; MC += pc;
              pCnt[Mr] = 0.f;
              int mn = nxt[Mr];
              nxt[pp] = mn; if (mn >= 0) prv[mn] = pp;
              Mr = pp;
              continue;
            }
          }
          int qq = nxt[Mr];
          if (qq >= 0) {
            float qs = pSum[qq], qc = pCnt[qq];
            if (qs * MC > MS * qc) {      // mean(right pool) > mean(M): absorb
              MS += qs; MC += qc;
              pCnt[qq] = 0.f;
              if (qq == stRk[sR]) rtail = true;
              int qn = nxt[qq];
              nxt[Mr] = qn; if (qn >= 0) prv[qn] = Mr;
              continue;
            }
          }
          break;
        }
        pSum[Mr] = MS; pCnt[Mr] = MC;
        if (Mr == shR[sL]) { shS[sL] = MS; shC[sL] = MC; }  // M reached group head
        if (rtail) { stRk[sL] = Mr; stS[sL] = MS; stC[sL] = MC; }
        else       { stRk[sL] = stRk[sR]; stS[sL] = stS[sR]; stC[sL] = stC[sR]; }
      } else {
        // no violation: concatenation only
        stRk[sL] = stRk[sR]; stS[sL] = stS[sR]; stC[sL] = stC[sR];
      }
    }
    __syncthreads();
  }
}

// Each active pool start writes clipped mean to its covered ranks;
// recover original index from key low bits, apply sign, add x.
__global__ void k_scatter(const u64* __restrict__ key,
                          const float* __restrict__ pSum, const float* __restrict__ pCnt,
                          const float* __restrict__ u, const float* __restrict__ x,
                          float* __restrict__ out, int n) {
  int i = blockIdx.x * blockDim.x + threadIdx.x;
  if (i >= n) return;
  float c = pCnt[i];
  if (c > 0.f) {
    float m = fmaxf(pSum[i] / c, 0.f);
    int e = i + (int)c;
    for (int k = i; k < e; ++k) {
      unsigned idx = ~(unsigned)(key[k] & 0xFFFFFFFFull);
      float d = u[idx] - x[idx];
      float v = (d > 0.f) ? m : ((d < 0.f) ? -m : 0.f);
      out[idx] = x[idx] + v;
    }
  }
}

extern "C" void kernel_launch(void* const* d_in, const int* in_sizes, int n_in,
                              void* d_out, int out_size, void* d_ws, size_t ws_size,
                              hipStream_t stream) {
  const float* u = (const float*)d_in[0];
  const float* x = (const float*)d_in[1];
  const float* w = (const float*)d_in[2];
  float* out = (float*)d_out;
  int n = in_sizes[0];          // 150528
  int npad = CHUNK;
  while (npad < n) npad <<= 1;  // 262144

  // workspace carve (~5.8 MB total)
  char* base = (char*)d_ws;
  u64* key      = (u64*)base;   base += (size_t)npad * 8;
  float* stkSum = (float*)base; base += (size_t)(n + NSEG) * 4;
  float* stkCnt = (float*)base; base += (size_t)(n + NSEG) * 4;
  float* pSum   = (float*)base; base += (size_t)n * 4;
  float* pCnt   = (float*)base; base += (size_t)n * 4;
  int* prv   = (int*)base;   base += (size_t)n * 4;
  int* nxt   = (int*)base;   base += (size_t)n * 4;
  int* headR = (int*)base;   base += (size_t)NSEG * 4;
  int* tailR = (int*)base;   base += (size_t)NSEG * 4;
  float* headS = (float*)base; base += (size_t)NSEG * 4;
  float* headC = (float*)base; base += (size_t)NSEG * 4;
  float* tailS = (float*)base; base += (size_t)NSEG * 4;
  float* tailC = (float*)base; base += (size_t)NSEG * 4;

  int nchunks = npad / CHUNK;
  hipLaunchKernelGGL(k_sort_chunk, dim3(nchunks), dim3(CTHREADS), 0, stream,
                     u, x, key, n);

  for (int k = CHUNK * 2; k <= npad; k <<= 1) {
    int p_top = 31 - __builtin_clz(k) - 1;   // log2(k) - 1
    while (p_top >= LOG_CHUNK) {
      int nl = p_top - LOG_CHUNK + 1;
      if (nl > 5) nl = 5;
      int p_lo = p_top - nl + 1;
      int threads = npad >> nl;
      dim3 g((threads + 255) / 256);
      switch (nl) {
        case 1: hipLaunchKernelGGL((k_merge_fused<1>), g, dim3(256), 0, stream, key, k, p_lo); break;
        case 2: hipLaunchKernelGGL((k_merge_fused<2>), g, dim3(256), 0, stream, key, k, p_lo); break;
        case 3: hipLaunchKernelGGL((k_merge_fused<3>), g, dim3(256), 0, stream, key, k, p_lo); break;
        case 4: hipLaunchKernelGGL((k_merge_fused<4>), g, dim3(256), 0, stream, key, k, p_lo); break;
        default: hipLaunchKernelGGL((k_merge_fused<5>), g, dim3(256), 0, stream, key, k, p_lo); break;
      }
      p_top = p_lo - 1;
    }
    hipLaunchKernelGGL(k_merge_shared, dim3(nchunks), dim3(CTHREADS), 0, stream, key, k);
  }

  int Lc = (n + NSEG - 1) / NSEG;  // 74
  hipLaunchKernelGGL(k_pava_seg, dim3(NSEG / 256), dim3(256), 0, stream,
                     key, w, stkSum, stkCnt, pSum, pCnt, prv, nxt,
                     headR, tailR, headS, headC, tailS, tailC, n, Lc);
  hipLaunchKernelGGL(k_merge_pools, dim3(1), dim3(1024), 0, stream,
                     pSum, pCnt, prv, nxt, headR, tailR, headS, headC, tailS, tailC);
  hipLaunchKernelGGL(k_scatter, dim3((n + 255) / 256), dim3(256), 0, stream,
                     key, pSum, pCnt, u, x, out, n);
}

// Round 5
// 213.516 us; speedup vs baseline: 1.4310x; 1.4310x over previous
//
#include <hip/hip_runtime.h>
#include <stdint.h>

typedef unsigned long long u64;

#define CHUNK 2048      // elements per LDS sort chunk
#define CTHREADS 1024   // threads per chunk block (2 elems/thread)
#define LOG_CHUNK 11
#define NSEG 2048       // parallel PAVA segments (boundary cache fits 48KB LDS)
#define PBLK 64         // threads per pava block (1 wave)
#define MAXLC 80        // max segment length supported (n <= NSEG*MAXLC)

__device__ __forceinline__ void cmpswap(u64& a, u64& b, bool desc) {
  bool sw = desc ? (a < b) : (a > b);
  if (sw) { u64 t = a; a = b; b = t; }
}

// Build composite keys (bits(|u-x|)<<32 | ~idx) and fully sort each
// 2048-chunk in LDS. Descending u64 == stable argsort(-abs).
__global__ void k_sort_chunk(const float* __restrict__ u, const float* __restrict__ x,
                             u64* __restrict__ key, int n) {
  __shared__ u64 s[CHUNK];
  int base = blockIdx.x * CHUNK;
  for (int q = 0; q < 2; ++q) {
    int g = base + threadIdx.x + q * CTHREADS;
    u64 kk = 0ull;
    if (g < n) {
      float d = u[g] - x[g];
      kk = ((u64)__float_as_uint(fabsf(d)) << 32) | (unsigned)(~(unsigned)g);
    }
    s[threadIdx.x + q * CTHREADS] = kk;
  }
  __syncthreads();
  for (int k = 2; k <= CHUNK; k <<= 1) {
    for (int j = k >> 1; j > 0; j >>= 1) {
      int t = threadIdx.x;
      int i = 2 * t - (t & (j - 1));
      bool desc = (((base + i) & k) == 0);
      cmpswap(s[i], s[i + j], desc);
      __syncthreads();
    }
  }
  key[base + threadIdx.x] = s[threadIdx.x];
  key[base + threadIdx.x + CTHREADS] = s[threadIdx.x + CTHREADS];
}

// Fused NL bitonic levels (j = 2^(p_lo+NL-1) .. 2^p_lo, all >= CHUNK) of
// stage k, done in registers: 2^NL keys per thread. All fused levels sit
// below bit log2(k), so the direction is uniform within the group.
template<int NL>
__global__ void k_merge_fused(u64* __restrict__ key, int k, int p_lo) {
  int t = blockIdx.x * blockDim.x + threadIdx.x;
  int jlo = 1 << p_lo;
  int low = t & (jlo - 1);
  int base = ((t >> p_lo) << (p_lo + NL)) | low;
  bool desc = ((base & k) == 0);
  u64 v[1 << NL];
#pragma unroll
  for (int m = 0; m < (1 << NL); ++m) v[m] = key[base + m * jlo];
#pragma unroll
  for (int lev = NL - 1; lev >= 0; --lev) {
    int st = 1 << lev;
#pragma unroll
    for (int m = 0; m < (1 << NL); ++m) {
      if ((m & st) == 0) cmpswap(v[m], v[m + st], desc);
    }
  }
#pragma unroll
  for (int m = 0; m < (1 << NL); ++m) key[base + m * jlo] = v[m];
}

// Fused j = 1024..1 levels of stage k, per 2048-chunk in LDS.
__global__ void k_merge_shared(u64* __restrict__ key, int k) {
  __shared__ u64 s[CHUNK];
  int base = blockIdx.x * CHUNK;
  s[threadIdx.x] = key[base + threadIdx.x];
  s[threadIdx.x + CTHREADS] = key[base + threadIdx.x + CTHREADS];
  __syncthreads();
  for (int j = CHUNK >> 1; j > 0; j >>= 1) {
    int t = threadIdx.x;
    int i = 2 * t - (t & (j - 1));
    bool desc = (((base + i) & k) == 0);
    cmpswap(s[i], s[i + j], desc);
    __syncthreads();
  }
  key[base + threadIdx.x] = s[threadIdx.x];
  key[base + threadIdx.x + CTHREADS] = s[threadIdx.x + CTHREADS];
}

// Per-thread sequential PAVA (non-increasing fit), fully LDS-resident:
// block of 64 threads covers 64 contiguous segments; yv = |diff|-w staged
// into LDS via coalesced global reads; the spill stack also lives in LDS,
// so the carried dependence never touches global memory (the R4 regression
// was the spill-store -> merge-reload vmcnt round trip per iteration).
// Emits pools as linked list (sum/cnt at pool-start rank, cnt=0 elsewhere)
// plus compact per-segment boundary-pool arrays for the merge kernel.
__global__ void k_pava_seg(const u64* __restrict__ key, const float* __restrict__ w,
                           float* __restrict__ pSum, float* __restrict__ pCnt,
                           int* __restrict__ prv, int* __restrict__ nxt,
                           int* __restrict__ headR, int* __restrict__ tailR,
                           float* __restrict__ headS, float* __restrict__ headC,
                           float* __restrict__ tailS, float* __restrict__ tailC,
                           int n, int Lc) {
  __shared__ float yv[PBLK * (MAXLC + 1)];
  __shared__ float stS_[PBLK * (MAXLC + 1)];
  __shared__ float stC_[PBLK * (MAXLC + 1)];
  int t = threadIdx.x;
  int tid = blockIdx.x * PBLK + t;
  int B0 = blockIdx.x * PBLK * Lc;
  int stride = Lc + 1;
  // cooperative coalesced staging: yv[seg][r] = |diff|(rank) - w(rank)
  const unsigned* kh = (const unsigned*)key;   // high dword of key = abs bits
  int tot = PBLK * Lc;
  for (int i = t; i < tot; i += PBLK) {
    int g = B0 + i;
    float v = 0.f;
    if (g < n) v = __uint_as_float(kh[2 * g + 1]) - w[g];
    yv[(i / Lc) * stride + (i % Lc)] = v;
  }
  __syncthreads();

  int s = tid * Lc;
  int e = min(s + Lc, n);
  if (s >= e) {
    if (tid < NSEG) { headR[tid] = -1; tailR[tid] = -1; }
    return;
  }
  int cnt = e - s;
  int lb = t * stride;        // this thread's LDS base
  float ts = 0.f, tc = 0.f;   // top pool
  float ss = 0.f, sc = 0.f;   // second pool (valid when depth >= 1)
  int depth = 0;              // pools below top; slots 0..depth-2 in LDS
  for (int r = 0; r < cnt; ++r) {
    float v = yv[lb + r];
    if (r > 0) {
      if (depth >= 1) { stS_[lb + depth - 1] = ss; stC_[lb + depth - 1] = sc; }
      ss = ts; sc = tc; ++depth;
    }
    ts = v; tc = 1.f;
    // merge while mean(top) > mean(second)  (cross-multiplied, cnts > 0)
    while (depth >= 1 && ts * sc > ss * tc) {
      ts += ss; tc += sc; --depth;
      if (depth >= 1) { ss = stS_[lb + depth - 1]; sc = stC_[lb + depth - 1]; }
    }
  }
  // emit pools bottom-to-top; pool j starts at cumulative-count offset
  int prevStart = -1;
  int start = s;
  float hS = 0.f, hC = 0.f, lS = 0.f, lC = 0.f;
  for (int j = 0; j <= depth; ++j) {
    float sj, cj;
    if (j == depth)          { sj = ts; cj = tc; }
    else if (j == depth - 1) { sj = ss; cj = sc; }
    else                     { sj = stS_[lb + j]; cj = stC_[lb + j]; }
    if (j == 0) { hS = sj; hC = cj; }
    lS = sj; lC = cj;
    pSum[start] = sj;
    pCnt[start] = cj;
    prv[start] = prevStart;
    if (prevStart >= 0) nxt[prevStart] = start;
    int c = (int)cj;
    for (int z = 1; z < c; ++z) pCnt[start + z] = 0.f;
    prevStart = start;
    start += c;
  }
  nxt[prevStart] = -1;
  headR[tid] = s;  tailR[tid] = prevStart;
  headS[tid] = hS; headC[tid] = hC;
  tailS[tid] = lS; tailC[tid] = lC;
}

// Hierarchical pairwise segment merge with LDS-cached group boundaries.
// Common path (no junction violation): LDS compare + 2 global stores, no
// dependent global loads. Rare cascades walk the global linked list.
// PAVA's fixed point is invariant to adjacent-merge order, so this is exact.
__global__ void k_merge_pools(float* __restrict__ pSum, float* __restrict__ pCnt,
                              int* __restrict__ prv, int* __restrict__ nxt,
                              const int* __restrict__ headR, const int* __restrict__ tailR,
                              const float* __restrict__ headS, const float* __restrict__ headC,
                              const float* __restrict__ tailS, const float* __restrict__ tailC) {
  __shared__ int shR[NSEG], stRk[NSEG];
  __shared__ float shS[NSEG], shC[NSEG], stS[NSEG], stC[NSEG];
  for (int i = threadIdx.x; i < NSEG; i += blockDim.x) {
    shR[i] = headR[i]; stRk[i] = tailR[i];
    shS[i] = headS[i]; shC[i] = headC[i];
    stS[i] = tailS[i]; stC[i] = tailC[i];
  }
  __syncthreads();
  for (int step = 1; step < NSEG; step <<= 1) {
    int pairs = NSEG / (2 * step);
    for (int p = threadIdx.x; p < pairs; p += blockDim.x) {
      int sL = p * 2 * step, sR = sL + step;
      int rR = shR[sR];
      if (rR < 0) continue;               // right group empty
      if (shR[sL] < 0) {                  // left empty: adopt right
        shR[sL] = rR; shS[sL] = shS[sR]; shC[sL] = shC[sR];
        stRk[sL] = stRk[sR]; stS[sL] = stS[sR]; stC[sL] = stC[sR];
        continue;
      }
      int lR = stRk[sL];
      float lS = stS[sL], lC = stC[sL];
      float rS = shS[sR], rC = shC[sR];
      nxt[lR] = rR; prv[rR] = lR;         // stitch lists
      if (rS * lC > lS * rC) {
        // violation at junction: cascade merge in global linked list
        float MS = lS + rS, MC = lC + rC;
        int Mr = lR;
        bool rtail = (rR == stRk[sR]);
        pCnt[rR] = 0.f;
        int nx = nxt[rR];
        nxt[Mr] = nx; if (nx >= 0) prv[nx] = Mr;
        for (;;) {
          int pp = prv[Mr];
          if (pp >= 0) {
            float ps = pSum[pp], pc = pCnt[pp];
            if (MS * pc > ps * MC) {      // mean(M) > mean(left pool): absorb
              MS += ps; MC += pc;
              pCnt[Mr] = 0.f;
              int mn = nxt[Mr];
              nxt[pp] = mn; if (mn >= 0) prv[mn] = pp;
              Mr = pp;
              continue;
            }
          }
          int qq = nxt[Mr];
          if (qq >= 0) {
            float qs = pSum[qq], qc = pCnt[qq];
            if (qs * MC > MS * qc) {      // mean(right pool) > mean(M): absorb
              MS += qs; MC += qc;
              pCnt[qq] = 0.f;
              if (qq == stRk[sR]) rtail = true;
              int qn = nxt[qq];
              nxt[Mr] = qn; if (qn >= 0) prv[qn] = Mr;
              continue;
            }
          }
          break;
        }
        pSum[Mr] = MS; pCnt[Mr] = MC;
        if (Mr == shR[sL]) { shS[sL] = MS; shC[sL] = MC; }  // M reached group head
        if (rtail) { stRk[sL] = Mr; stS[sL] = MS; stC[sL] = MC; }
        else       { stRk[sL] = stRk[sR]; stS[sL] = stS[sR]; stC[sL] = stC[sR]; }
      } else {
        // no violation: concatenation only
        stRk[sL] = stRk[sR]; stS[sL] = stS[sR]; stC[sL] = stC[sR];
      }
    }
    __syncthreads();
  }
}

// Each active pool start writes clipped mean to its covered ranks;
// recover original index from key low bits, apply sign, add x.
__global__ void k_scatter(const u64* __restrict__ key,
                          const float* __restrict__ pSum, const float* __restrict__ pCnt,
                          const float* __restrict__ u, const float* __restrict__ x,
                          float* __restrict__ out, int n) {
  int i = blockIdx.x * blockDim.x + threadIdx.x;
  if (i >= n) return;
  float c = pCnt[i];
  if (c > 0.f) {
    float m = fmaxf(pSum[i] / c, 0.f);
    int e = i + (int)c;
    for (int k = i; k < e; ++k) {
      unsigned idx = ~(unsigned)(key[k] & 0xFFFFFFFFull);
      float d = u[idx] - x[idx];
      float v = (d > 0.f) ? m : ((d < 0.f) ? -m : 0.f);
      out[idx] = x[idx] + v;
    }
  }
}

extern "C" void kernel_launch(void* const* d_in, const int* in_sizes, int n_in,
                              void* d_out, int out_size, void* d_ws, size_t ws_size,
                              hipStream_t stream) {
  const float* u = (const float*)d_in[0];
  const float* x = (const float*)d_in[1];
  const float* w = (const float*)d_in[2];
  float* out = (float*)d_out;
  int n = in_sizes[0];          // 150528
  int npad = CHUNK;
  while (npad < n) npad <<= 1;  // 262144

  // workspace carve (~4.6 MB total)
  char* base = (char*)d_ws;
  u64* key      = (u64*)base;   base += (size_t)npad * 8;
  float* pSum   = (float*)base; base += (size_t)n * 4;
  float* pCnt   = (float*)base; base += (size_t)n * 4;
  int* prv   = (int*)base;   base += (size_t)n * 4;
  int* nxt   = (int*)base;   base += (size_t)n * 4;
  int* headR = (int*)base;   base += (size_t)NSEG * 4;
  int* tailR = (int*)base;   base += (size_t)NSEG * 4;
  float* headS = (float*)base; base += (size_t)NSEG * 4;
  float* headC = (float*)base; base += (size_t)NSEG * 4;
  float* tailS = (float*)base; base += (size_t)NSEG * 4;
  float* tailC = (float*)base; base += (size_t)NSEG * 4;

  int nchunks = npad / CHUNK;
  hipLaunchKernelGGL(k_sort_chunk, dim3(nchunks), dim3(CTHREADS), 0, stream,
                     u, x, key, n);

  for (int k = CHUNK * 2; k <= npad; k <<= 1) {
    int p_top = 31 - __builtin_clz(k) - 1;   // log2(k) - 1
    while (p_top >= LOG_CHUNK) {
      int nl = p_top - LOG_CHUNK + 1;
      if (nl > 5) nl = 5;
      int p_lo = p_top - nl + 1;
      int threads = npad >> nl;
      dim3 g((threads + 255) / 256);
      switch (nl) {
        case 1: hipLaunchKernelGGL((k_merge_fused<1>), g, dim3(256), 0, stream, key, k, p_lo); break;
        case 2: hipLaunchKernelGGL((k_merge_fused<2>), g, dim3(256), 0, stream, key, k, p_lo); break;
        case 3: hipLaunchKernelGGL((k_merge_fused<3>), g, dim3(256), 0, stream, key, k, p_lo); break;
        case 4: hipLaunchKernelGGL((k_merge_fused<4>), g, dim3(256), 0, stream, key, k, p_lo); break;
        default: hipLaunchKernelGGL((k_merge_fused<5>), g, dim3(256), 0, stream, key, k, p_lo); break;
      }
      p_top = p_lo - 1;
    }
    hipLaunchKernelGGL(k_merge_shared, dim3(nchunks), dim3(CTHREADS), 0, stream, key, k);
  }

  int Lc = (n + NSEG - 1) / NSEG;  // 74  (<= MAXLC)
  hipLaunchKernelGGL(k_pava_seg, dim3(NSEG / PBLK), dim3(PBLK), 0, stream,
                     key, w, pSum, pCnt, prv, nxt,
                     headR, tailR, headS, headC, tailS, tailC, n, Lc);
  hipLaunchKernelGGL(k_merge_pools, dim3(1), dim3(1024), 0, stream,
                     pSum, pCnt, prv, nxt, headR, tailR, headS, headC, tailS, tailC);
  hipLaunchKernelGGL(k_scatter, dim3((n + 255) / 256), dim3(256), 0, stream,
                     key, pSum, pCnt, u, x, out, n);
}